// Round 3
// baseline (88.817 us; speedup 1.0000x reference)
//
#include <hip/hip_runtime.h>
#include <math.h>

// N=32768 tokens, B=32 batches, S=1024 keys/batch, H=512, OUT=32.
//
// Rank-2 collapse: score(i,j) = x_i^T (scale*Wq Wk^T) x_j  (2x2 M).
// w_i = softmax-weighted mean of x_j (2-vector). Softmax shift = 0: worst-case
// |score| <= |u||x| ~ 57 -> sum e^s <= ~8e26 < fp32 max; shift-invariant.
// BN folds into pair-SoA {A0,A1,C}; P = PReLU(w0*A0+w1*A1+C).
// y = P @ Wout + bout as bf16 MFMA 16x16x32 (R3-proven layouts).
//
// R10 = R9 + async-STAGE split of the Wout pack (T14):
//  - 64 Wout scalar loads issued at kernel entry, held in VGPRs (reg headroom:
//    2 waves/SIMD needs <=256 VGPR, we are ~155)
//  - cvt_pk + ds_write of bfr moved to AFTER the softmax accumulation loop,
//    before the existing reduction barrier (which now also guards bfr).
//    HBM/L2 latency hides under ~4000 cycles of softmax; the pack VALU fills
//    softmax trans-pipe stall slots. Barrier count unchanged (first barrier
//    guards xs+mred only; bfr not read until after second barrier).
//  - packed f32 math + v_cvt_pk_bf16_f32 as in R9 (compiler-selected VOP3P)
// 512 blocks x 256 thr (2 blocks/CU, 2 waves/SIMD).

#define H_DIM   512
#define OUT_DIM 32
#define S_LEN   1024
#define THREADS 256
#define NW 4

#if __has_builtin(__builtin_amdgcn_exp2f)
#define EXP2(x) __builtin_amdgcn_exp2f(x)
#else
#define EXP2(x) exp2f(x)
#endif

typedef __attribute__((ext_vector_type(8))) short bf16x8;
typedef __attribute__((ext_vector_type(4))) float f32x4;
typedef __attribute__((ext_vector_type(2))) float f32x2;

__device__ __forceinline__ f32x2 pkfma(f32x2 a, f32x2 b, f32x2 c) {
    return __builtin_elementwise_fma(a, b, c);
}
// 2x f32 -> packed bf16 (lo from %1, hi from %2), RNE — matches old rne_bf16.
__device__ __forceinline__ unsigned int cvt_pk_bf16(float lo, float hi) {
    unsigned int r;
    asm("v_cvt_pk_bf16_f32 %0, %1, %2" : "=v"(r) : "v"(lo), "v"(hi));
    return r;
}

union frag_cast { unsigned int u[4]; int4 i4; bf16x8 v; };

__global__ __launch_bounds__(THREADS)
void fused_attn_kernel(const float* __restrict__ x,
                       const float* __restrict__ Wq,
                       const float* __restrict__ Wk,
                       const float* __restrict__ Wv,
                       const float* __restrict__ bn_gamma,
                       const float* __restrict__ bn_beta,
                       const float* __restrict__ bn_mean,
                       const float* __restrict__ bn_var,
                       const float* __restrict__ prelu_a,
                       const float* __restrict__ Wout,
                       const float* __restrict__ bout,
                       float* __restrict__ out)
{
    __shared__ __align__(16) float xsx[S_LEN]; // 4 KB, SoA key x-coords
    __shared__ __align__(16) float xsy[S_LEN]; // 4 KB, SoA key y-coords
    __shared__ float4 a01s[H_DIM / 2];        // 4 KB: {A0[2p],A0[2p+1],A1[2p],A1[2p+1]}
    __shared__ float2 cps[H_DIM / 2];         // 2 KB: {C[2p],C[2p+1]}
    __shared__ unsigned int bfr[32 * 64 * 4]; // 32 KB: bf16 B-frags, R3 ws layout
    __shared__ float redl[NW][64], redw0[NW][64], redw1[NW][64]; // 3 KB
    __shared__ float mred[NW][4];

    const int t    = threadIdx.x;
    const int lane = t & 63;
    const int q    = __builtin_amdgcn_readfirstlane(t >> 6);  // wave id 0..3
    const int b    = blockIdx.x >> 4;         // 16 blocks per batch
    const int tile = blockIdx.x & 15;
    const float scale = 0.044194173824159216f;  // 1/sqrt(512)
    const float L2E   = 1.4426950408889634f;

    // ---- async-STAGE issue: 64 Wout loads into regs (consumed post-softmax).
    // Per-thread decode (i = k*256 + t, t<256 => bits 0..7 of i are t):
    //   c=t&15, jj=(t>>4)&3, quad=(t>>6)&3, s=k&15, nt=k>>4
    const int c    = t & 15;
    const int jj4  = (t >> 4) & 3;
    const int qd   = (t >> 6) & 3;
    const int hb   = qd * 8 + 2 * jj4;
    float wo0[32], wo1[32];
    #pragma unroll
    for (int k = 0; k < 32; ++k) {
        const int s  = k & 15;
        const int nt = k >> 4;
        const int h  = s * 32 + hb;
        const int o  = nt * 16 + c;
        wo0[k] = Wout[h * 32 + o];
        wo1[k] = Wout[(h + 1) * 32 + o];
    }

    // ---- stage batch x as SoA (tokens 2t,2t+1 per float4) ----
    const float4* xg = (const float4*)(x + (size_t)b * (S_LEN * 2));
    f32x2* xsx2 = (f32x2*)xsx;
    f32x2* xsy2 = (f32x2*)xsy;
    {
        float4 v0 = xg[t];
        float4 v1 = xg[t + 256];
        f32x2 a = {v0.x, v0.z}; xsx2[t] = a;
        f32x2 cy = {v0.y, v0.w}; xsy2[t] = cy;
        f32x2 d = {v1.x, v1.z}; xsx2[t + 256] = d;
        f32x2 e = {v1.y, v1.w}; xsy2[t + 256] = e;
    }

    // ---- fold BN into pair-SoA ABC (pair p = t, h = 2t, 2t+1) ----
    {
        const float2 gm = ((const float2*)bn_gamma)[t];
        const float2 vr = ((const float2*)bn_var)[t];
        const float2 bt = ((const float2*)bn_beta)[t];
        const float2 mn = ((const float2*)bn_mean)[t];
        const float2 wv0 = ((const float2*)Wv)[t];             // Wv[0][2t..]
        const float2 wv1 = ((const float2*)(Wv + H_DIM))[t];   // Wv[1][2t..]
        float g0 = gm.x * rsqrtf(vr.x + 1e-5f);
        float g1 = gm.y * rsqrtf(vr.y + 1e-5f);
        a01s[t] = make_float4(wv0.x * g0, wv0.y * g1, wv1.x * g0, wv1.y * g1);
        cps[t]  = make_float2(bt.x - mn.x * g0, bt.y - mn.y * g1);
    }

    // ---- M = Wq Wk^T partials ----
    {
        float m00 = 0.f, m01 = 0.f, m10 = 0.f, m11 = 0.f;
        #pragma unroll
        for (int k = 0; k < 2; ++k) {
            int h = t + k * 256;
            float a0 = Wq[h], a1 = Wq[H_DIM + h];
            float b0 = Wk[h], b1 = Wk[H_DIM + h];
            m00 = fmaf(a0, b0, m00); m01 = fmaf(a0, b1, m01);
            m10 = fmaf(a1, b0, m10); m11 = fmaf(a1, b1, m11);
        }
        #pragma unroll
        for (int off = 32; off >= 1; off >>= 1) {
            m00 += __shfl_xor(m00, off); m01 += __shfl_xor(m01, off);
            m10 += __shfl_xor(m10, off); m11 += __shfl_xor(m11, off);
        }
        if (lane == 0) {
            mred[q][0] = m00; mred[q][1] = m01;
            mred[q][2] = m10; mred[q][3] = m11;
        }
    }
    __syncthreads();   // xs*, a01s/cps, mred visible (bfr NOT yet)

    float m00 = (mred[0][0] + mred[1][0] + mred[2][0] + mred[3][0]) * scale;
    float m01 = (mred[0][1] + mred[1][1] + mred[2][1] + mred[3][1]) * scale;
    float m10 = (mred[0][2] + mred[1][2] + mred[2][2] + mred[3][2]) * scale;
    float m11 = (mred[0][3] + mred[1][3] + mred[2][3] + mred[3][3]) * scale;

    // ---- per-token u (lane = token), no shift (log2e folded) ----
    const float xtx = xsx[tile * 64 + lane];
    const float xty = xsy[tile * 64 + lane];
    const float u0L = fmaf(xtx, m00, xty * m10) * L2E;
    const float u1L = fmaf(xtx, m01, xty * m11) * L2E;
    const f32x2 u0L2 = {u0L, u0L};
    const f32x2 u1L2 = {u1L, u1L};

    // ---- fused softmax pass: wave q covers keys [q*256, q*256+256) ----
    // 4 keys/iter; packed f32 pairs (even/odd accumulation chains).
    f32x2 l2  = {0.f, 0.f};
    f32x2 w02 = {0.f, 0.f};
    f32x2 w12 = {0.f, 0.f};
    const float4* kx4 = (const float4*)(xsx + q * 256);
    const float4* ky4 = (const float4*)(xsy + q * 256);
    #pragma unroll 4
    for (int i = 0; i < 64; ++i) {
        float4 kx = kx4[i];                 // wave-uniform addr -> broadcast
        float4 ky = ky4[i];
        f32x2 kxa = {kx.x, kx.y};
        f32x2 kxb = {kx.z, kx.w};
        f32x2 kya = {ky.x, ky.y};
        f32x2 kyb = {ky.z, ky.w};
        f32x2 arga = pkfma(u0L2, kxa, u1L2 * kya);
        f32x2 argb = pkfma(u0L2, kxb, u1L2 * kyb);
        f32x2 ea = {EXP2(arga.x), EXP2(arga.y)};
        f32x2 eb = {EXP2(argb.x), EXP2(argb.y)};
        l2  = l2 + ea + eb;
        w02 = pkfma(ea, kxa, w02);
        w02 = pkfma(eb, kxb, w02);
        w12 = pkfma(ea, kya, w12);
        w12 = pkfma(eb, kyb, w12);
    }

    // ---- async-STAGE write: pack held Wout regs -> bfr (R3 flat layout) ----
    // F = (nt*16+s)*256 + (quad*16+c)*4 + jj
    #pragma unroll
    for (int k = 0; k < 32; ++k) {
        const int s  = k & 15;
        const int nt = k >> 4;
        const int F  = (nt * 16 + s) * 256 + (qd * 16 + c) * 4 + jj4;
        bfr[F] = cvt_pk_bf16(wo0[k], wo1[k]);
    }

    float l  = l2.x + l2.y;
    float w0 = w02.x + w02.y;
    float w1 = w12.x + w12.y;
    redl[q][lane] = l; redw0[q][lane] = w0; redw1[q][lane] = w1;
    __syncthreads();   // red arrays AND bfr visible
    l  = redl[0][lane]  + redl[1][lane]  + redl[2][lane]  + redl[3][lane];
    w0 = redw0[0][lane] + redw0[1][lane] + redw0[2][lane] + redw0[3][lane];
    w1 = redw1[0][lane] + redw1[1][lane] + redw1[2][lane] + redw1[3][lane];
    const float inv = 1.0f / l;
    w0 *= inv; w1 *= inv;

    // redistribute: wave q's MFMA tile = tokens q*16..q*16+15; m = lane&15
    const int src = q * 16 + (lane & 15);
    const float w0t = __shfl(w0, src);
    const float w1t = __shfl(w1, src);
    const f32x2 w0t2 = {w0t, w0t};
    const f32x2 w1t2 = {w1t, w1t};

    // ---- MFMA epilogue: y[16 tok x 32 out] = P[16 x 512] @ Wout[512 x 32] ----
    // PReLU(z) = 0.5(1+a)z + 0.5(1-a)|z|  (exact for both signs)
    const float ap = prelu_a[0];
    const f32x2 ca2 = {0.5f * (1.f + ap), 0.5f * (1.f + ap)};
    const f32x2 cb2 = {0.5f * (1.f - ap), 0.5f * (1.f - ap)};
    const int quad = lane >> 4;
    f32x4 acc0 = {0.f, 0.f, 0.f, 0.f};
    f32x4 acc1 = {0.f, 0.f, 0.f, 0.f};
    const int4* bsrc = (const int4*)bfr;

    for (int s = 0; s < 16; ++s) {
        frag_cast bf0, bf1;                 // ds_read_b128, 2-way alias = free
        bf0.i4 = bsrc[s * 64 + lane];
        bf1.i4 = bsrc[(16 + s) * 64 + lane];
        const int hb2 = s * 16 + quad * 4;  // h-pair index base
        frag_cast af;
        #pragma unroll
        for (int jj = 0; jj < 4; ++jj) {
            float4 a = a01s[hb2 + jj];      // broadcast ds_read_b128
            float2 cc2 = cps[hb2 + jj];     // broadcast ds_read_b64
            f32x2 a0 = {a.x, a.y};
            f32x2 a1 = {a.z, a.w};
            f32x2 cc = {cc2.x, cc2.y};
            f32x2 z  = pkfma(w0t2, a0, pkfma(w1t2, a1, cc));
            f32x2 az = __builtin_elementwise_abs(z);
            f32x2 p  = pkfma(ca2, z, cb2 * az);
            af.u[jj] = cvt_pk_bf16(p.x, p.y);
        }
        acc0 = __builtin_amdgcn_mfma_f32_16x16x32_bf16(af.v, bf0.v, acc0, 0, 0, 0);
        acc1 = __builtin_amdgcn_mfma_f32_16x16x32_bf16(af.v, bf1.v, acc1, 0, 0, 0);
    }

    // ---- store: D col=lane&15 (out), row=quad*4+r (token) ----
    const size_t base = (size_t)(b * S_LEN + tile * 64) * OUT_DIM;
    const int o0 = lane & 15;
    const float bo0 = bout[o0], bo1 = bout[16 + o0];
    #pragma unroll
    for (int r = 0; r < 4; ++r) {
        const int tt = q * 16 + quad * 4 + r;
        out[base + tt * 32 + o0]      = acc0[r] + bo0;
        out[base + tt * 32 + 16 + o0] = acc1[r] + bo1;
    }
}

extern "C" void kernel_launch(void* const* d_in, const int* in_sizes, int n_in,
                              void* d_out, int out_size, void* d_ws, size_t ws_size,
                              hipStream_t stream) {
    const float* x    = (const float*)d_in[0];
    const float* Wq   = (const float*)d_in[2];
    const float* Wk   = (const float*)d_in[3];
    const float* Wv   = (const float*)d_in[4];
    const float* gam  = (const float*)d_in[5];
    const float* bet  = (const float*)d_in[6];
    const float* mean = (const float*)d_in[7];
    const float* var  = (const float*)d_in[8];
    const float* pa   = (const float*)d_in[9];
    const float* Wout = (const float*)d_in[10];
    const float* bo   = (const float*)d_in[11];
    float* out = (float*)d_out;

    const int N = in_sizes[0] / 2;          // 32768 tokens
    const int blocks = N / 64;              // 512
    hipLaunchKernelGGL(fused_attn_kernel, dim3(blocks), dim3(THREADS), 0, stream,
                       x, Wq, Wk, Wv, gam, bet, mean, var, pa, Wout, bo, out);
}

// Round 4
// 88.311 us; speedup vs baseline: 1.0057x; 1.0057x over previous
//
#include <hip/hip_runtime.h>
#include <math.h>

// N=32768 tokens, B=32 batches, S=1024 keys/batch, H=512, OUT=32.
//
// Rank-2 collapse: score(i,j) = x_i^T (scale*Wq Wk^T) x_j  (2x2 M).
// w_i = softmax-weighted mean of x_j (2-vector). Softmax shift = 0: worst-case
// |score| <= |u||x| ~ 57 -> sum e^s <= ~8e26 < fp32 max; shift-invariant.
// BN folds into pair-SoA {A0,A1,C}; P = PReLU(w0*A0+w1*A1+C).
// y = P @ Wout + bout as bf16 MFMA 16x16x32 (R3-proven layouts).
//
// R11 = R9 (R10's async-STAGE split reverted: +0.9us regression, latency was
// already TLP-hidden and 64 held VGPRs hurt) + wave-local softmax:
//  - wave q owns tokens q*16..q*16+15 (its own MFMA tile); lane l handles
//    token l&15, key-quarter l>>4 (256 contiguous keys -- same chunk
//    boundaries as R9's per-wave split, fp association ~identical)
//  - reduction = 2x __shfl_xor(16,32) x {l,w0,w1}; NO second barrier, no
//    red[] LDS arrays, no redistribute shuffle (lane&15 == MFMA A-row m)
//  - key quarters padded +4 floats (stride 260) so the 4 distinct
//    ds_read_b128 addrs/wave hit disjoint banks (else 4-way conflict)
// 512 blocks x 256 thr (2 blocks/CU, 2 waves/SIMD).

#define H_DIM   512
#define OUT_DIM 32
#define S_LEN   1024
#define QSTRIDE 260          // 256-key quarter + 4-float pad (bank skew)
#define XS_LEN  1040         // 4 * QSTRIDE
#define THREADS 256
#define NW 4

#if __has_builtin(__builtin_amdgcn_exp2f)
#define EXP2(x) __builtin_amdgcn_exp2f(x)
#else
#define EXP2(x) exp2f(x)
#endif

typedef __attribute__((ext_vector_type(8))) short bf16x8;
typedef __attribute__((ext_vector_type(4))) float f32x4;
typedef __attribute__((ext_vector_type(2))) float f32x2;

__device__ __forceinline__ f32x2 pkfma(f32x2 a, f32x2 b, f32x2 c) {
    return __builtin_elementwise_fma(a, b, c);
}
// 2x f32 -> packed bf16 (lo from %1, hi from %2), RNE — matches old rne_bf16.
__device__ __forceinline__ unsigned int cvt_pk_bf16(float lo, float hi) {
    unsigned int r;
    asm("v_cvt_pk_bf16_f32 %0, %1, %2" : "=v"(r) : "v"(lo), "v"(hi));
    return r;
}

union frag_cast { unsigned int u[4]; int4 i4; bf16x8 v; };

__global__ __launch_bounds__(THREADS)
void fused_attn_kernel(const float* __restrict__ x,
                       const float* __restrict__ Wq,
                       const float* __restrict__ Wk,
                       const float* __restrict__ Wv,
                       const float* __restrict__ bn_gamma,
                       const float* __restrict__ bn_beta,
                       const float* __restrict__ bn_mean,
                       const float* __restrict__ bn_var,
                       const float* __restrict__ prelu_a,
                       const float* __restrict__ Wout,
                       const float* __restrict__ bout,
                       float* __restrict__ out)
{
    __shared__ __align__(16) float xsx[XS_LEN]; // 4.06 KB, SoA key x (padded)
    __shared__ __align__(16) float xsy[XS_LEN]; // 4.06 KB, SoA key y (padded)
    __shared__ float4 a01s[H_DIM / 2];        // 4 KB: {A0[2p],A0[2p+1],A1[2p],A1[2p+1]}
    __shared__ float2 cps[H_DIM / 2];         // 2 KB: {C[2p],C[2p+1]}
    __shared__ unsigned int bfr[32 * 64 * 4]; // 32 KB: bf16 B-frags, R3 ws layout
    __shared__ float mred[NW][4];

    const int t    = threadIdx.x;
    const int lane = t & 63;
    const int q    = __builtin_amdgcn_readfirstlane(t >> 6);  // wave id 0..3
    const int b    = blockIdx.x >> 4;         // 16 blocks per batch
    const int tile = blockIdx.x & 15;
    const float scale = 0.044194173824159216f;  // 1/sqrt(512)
    const float L2E   = 1.4426950408889634f;

    // ---- stage batch x as SoA (tokens 2t,2t+1 per float4), quarter-padded ----
    const float4* xg = (const float4*)(x + (size_t)b * (S_LEN * 2));
    f32x2* xsx2 = (f32x2*)xsx;
    f32x2* xsy2 = (f32x2*)xsy;
    {
        float4 v0 = xg[t];
        float4 v1 = xg[t + 256];
        const int i0 = t + (t >> 7) * 2;              // key 2t quarter pad
        const int i1 = (t + 256) + ((t >> 7) + 2) * 2; // key 2t+512 quarter pad
        f32x2 a = {v0.x, v0.z}; xsx2[i0] = a;
        f32x2 cy = {v0.y, v0.w}; xsy2[i0] = cy;
        f32x2 d = {v1.x, v1.z}; xsx2[i1] = d;
        f32x2 e = {v1.y, v1.w}; xsy2[i1] = e;
    }

    // ---- fold BN into pair-SoA ABC (pair p = t, h = 2t, 2t+1) ----
    {
        const float2 gm = ((const float2*)bn_gamma)[t];
        const float2 vr = ((const float2*)bn_var)[t];
        const float2 bt = ((const float2*)bn_beta)[t];
        const float2 mn = ((const float2*)bn_mean)[t];
        const float2 wv0 = ((const float2*)Wv)[t];             // Wv[0][2t..]
        const float2 wv1 = ((const float2*)(Wv + H_DIM))[t];   // Wv[1][2t..]
        float g0 = gm.x * rsqrtf(vr.x + 1e-5f);
        float g1 = gm.y * rsqrtf(vr.y + 1e-5f);
        a01s[t] = make_float4(wv0.x * g0, wv0.y * g1, wv1.x * g0, wv1.y * g1);
        cps[t]  = make_float2(bt.x - mn.x * g0, bt.y - mn.y * g1);
    }

    // ---- M = Wq Wk^T partials ----
    {
        float m00 = 0.f, m01 = 0.f, m10 = 0.f, m11 = 0.f;
        #pragma unroll
        for (int k = 0; k < 2; ++k) {
            int h = t + k * 256;
            float a0 = Wq[h], a1 = Wq[H_DIM + h];
            float b0 = Wk[h], b1 = Wk[H_DIM + h];
            m00 = fmaf(a0, b0, m00); m01 = fmaf(a0, b1, m01);
            m10 = fmaf(a1, b0, m10); m11 = fmaf(a1, b1, m11);
        }
        #pragma unroll
        for (int off = 32; off >= 1; off >>= 1) {
            m00 += __shfl_xor(m00, off); m01 += __shfl_xor(m01, off);
            m10 += __shfl_xor(m10, off); m11 += __shfl_xor(m11, off);
        }
        if (lane == 0) {
            mred[q][0] = m00; mred[q][1] = m01;
            mred[q][2] = m10; mred[q][3] = m11;
        }
    }

    // ---- pack Wout -> bf16 B-frags in LDS (R3 setup's exact flat layout) ----
    // flat u32 index F = f*256 + l*4 + jj, f = nt*16+s, l = quad*16+c:
    //   bfr[F] = pack(Wout[s*32+quad*8+2jj][nt*16+c], Wout[s*32+quad*8+2jj+1][nt*16+c])
    // thread mapping i = k*256+t decodes c fastest for coalesced Wout reads.
    #pragma unroll
    for (int k = 0; k < 32; ++k) {
        int i    = k * 256 + t;
        int c    = i & 15;
        int jj   = (i >> 4) & 3;
        int quad = (i >> 6) & 3;
        int s    = (i >> 8) & 15;
        int nt   = (i >> 12) & 1;
        int h    = s * 32 + quad * 8 + 2 * jj;
        int o    = nt * 16 + c;
        float f0 = Wout[h * 32 + o];
        float f1 = Wout[(h + 1) * 32 + o];
        int F = (nt * 16 + s) * 256 + (quad * 16 + c) * 4 + jj;
        bfr[F] = cvt_pk_bf16(f0, f1);
    }
    __syncthreads();   // xs*, a01s/cps, mred, bfr all visible — ONLY barrier

    float m00 = (mred[0][0] + mred[1][0] + mred[2][0] + mred[3][0]) * scale;
    float m01 = (mred[0][1] + mred[1][1] + mred[2][1] + mred[3][1]) * scale;
    float m10 = (mred[0][2] + mred[1][2] + mred[2][2] + mred[3][2]) * scale;
    float m11 = (mred[0][3] + mred[1][3] + mred[2][3] + mred[3][3]) * scale;

    // ---- per-lane token: m = lane&15 of wave q's tile; key-quarter g = lane>>4
    const int m  = lane & 15;
    const int g  = lane >> 4;
    const int jt = tile * 64 + q * 16 + m;            // token's key index
    const int jo = jt + ((jt >> 8) << 2);             // padded offset
    const float xtx = xsx[jo];
    const float xty = xsy[jo];
    const float u0L = fmaf(xtx, m00, xty * m10) * L2E;
    const float u1L = fmaf(xtx, m01, xty * m11) * L2E;
    const f32x2 u0L2 = {u0L, u0L};
    const f32x2 u1L2 = {u1L, u1L};

    // ---- fused softmax: lane covers keys [g*256, g*256+256) for token m ----
    // 4 keys/iter; packed f32 pairs. 4 distinct b128 addrs/wave, bank-skewed
    // by the +4 pad (QSTRIDE=260 -> bank offset 4g) -> conflict-free.
    f32x2 l2  = {0.f, 0.f};
    f32x2 w02 = {0.f, 0.f};
    f32x2 w12 = {0.f, 0.f};
    const float4* kx4 = (const float4*)(xsx + g * QSTRIDE);
    const float4* ky4 = (const float4*)(xsy + g * QSTRIDE);
    #pragma unroll 4
    for (int i = 0; i < 64; ++i) {
        float4 kx = kx4[i];
        float4 ky = ky4[i];
        f32x2 kxa = {kx.x, kx.y};
        f32x2 kxb = {kx.z, kx.w};
        f32x2 kya = {ky.x, ky.y};
        f32x2 kyb = {ky.z, ky.w};
        f32x2 arga = pkfma(u0L2, kxa, u1L2 * kya);
        f32x2 argb = pkfma(u0L2, kxb, u1L2 * kyb);
        f32x2 ea = {EXP2(arga.x), EXP2(arga.y)};
        f32x2 eb = {EXP2(argb.x), EXP2(argb.y)};
        l2  = l2 + ea + eb;
        w02 = pkfma(ea, kxa, w02);
        w02 = pkfma(eb, kxb, w02);
        w12 = pkfma(ea, kya, w12);
        w12 = pkfma(eb, kyb, w12);
    }
    float l  = l2.x + l2.y;
    float w0 = w02.x + w02.y;
    float w1 = w12.x + w12.y;
    // cross-quarter reduce within lane-groups {m, m+16, m+32, m+48}
    l  += __shfl_xor(l, 16);  l  += __shfl_xor(l, 32);
    w0 += __shfl_xor(w0, 16); w0 += __shfl_xor(w0, 32);
    w1 += __shfl_xor(w1, 16); w1 += __shfl_xor(w1, 32);
    const float inv = 1.0f / l;
    const float w0t = w0 * inv;                       // lane&15 == A-row m
    const float w1t = w1 * inv;
    const f32x2 w0t2 = {w0t, w0t};
    const f32x2 w1t2 = {w1t, w1t};

    // ---- MFMA epilogue: y[16 tok x 32 out] = P[16 x 512] @ Wout[512 x 32] ----
    // PReLU(z) = 0.5(1+a)z + 0.5(1-a)|z|  (exact for both signs)
    const float ap = prelu_a[0];
    const f32x2 ca2 = {0.5f * (1.f + ap), 0.5f * (1.f + ap)};
    const f32x2 cb2 = {0.5f * (1.f - ap), 0.5f * (1.f - ap)};
    const int quad = lane >> 4;
    f32x4 acc0 = {0.f, 0.f, 0.f, 0.f};
    f32x4 acc1 = {0.f, 0.f, 0.f, 0.f};
    const int4* bsrc = (const int4*)bfr;

    for (int s = 0; s < 16; ++s) {
        frag_cast bf0, bf1;                 // ds_read_b128, 2-way alias = free
        bf0.i4 = bsrc[s * 64 + lane];
        bf1.i4 = bsrc[(16 + s) * 64 + lane];
        const int hb2 = s * 16 + quad * 4;  // h-pair index base
        frag_cast af;
        #pragma unroll
        for (int jj = 0; jj < 4; ++jj) {
            float4 a = a01s[hb2 + jj];      // broadcast ds_read_b128
            float2 cc2 = cps[hb2 + jj];     // broadcast ds_read_b64
            f32x2 a0 = {a.x, a.y};
            f32x2 a1 = {a.z, a.w};
            f32x2 cc = {cc2.x, cc2.y};
            f32x2 z  = pkfma(w0t2, a0, pkfma(w1t2, a1, cc));
            f32x2 az = __builtin_elementwise_abs(z);
            f32x2 p  = pkfma(ca2, z, cb2 * az);
            af.u[jj] = cvt_pk_bf16(p.x, p.y);
        }
        acc0 = __builtin_amdgcn_mfma_f32_16x16x32_bf16(af.v, bf0.v, acc0, 0, 0, 0);
        acc1 = __builtin_amdgcn_mfma_f32_16x16x32_bf16(af.v, bf1.v, acc1, 0, 0, 0);
    }

    // ---- store: D col=lane&15 (out), row=quad*4+r (token) ----
    const size_t base = (size_t)(b * S_LEN + tile * 64) * OUT_DIM;
    const int o0 = lane & 15;
    const float bo0 = bout[o0], bo1 = bout[16 + o0];
    #pragma unroll
    for (int r = 0; r < 4; ++r) {
        const int tt = q * 16 + quad * 4 + r;
        out[base + tt * 32 + o0]      = acc0[r] + bo0;
        out[base + tt * 32 + 16 + o0] = acc1[r] + bo1;
    }
}

extern "C" void kernel_launch(void* const* d_in, const int* in_sizes, int n_in,
                              void* d_out, int out_size, void* d_ws, size_t ws_size,
                              hipStream_t stream) {
    const float* x    = (const float*)d_in[0];
    const float* Wq   = (const float*)d_in[2];
    const float* Wk   = (const float*)d_in[3];
    const float* Wv   = (const float*)d_in[4];
    const float* gam  = (const float*)d_in[5];
    const float* bet  = (const float*)d_in[6];
    const float* mean = (const float*)d_in[7];
    const float* var  = (const float*)d_in[8];
    const float* pa   = (const float*)d_in[9];
    const float* Wout = (const float*)d_in[10];
    const float* bo   = (const float*)d_in[11];
    float* out = (float*)d_out;

    const int N = in_sizes[0] / 2;          // 32768 tokens
    const int blocks = N / 64;              // 512
    hipLaunchKernelGGL(fused_attn_kernel, dim3(blocks), dim3(THREADS), 0, stream,
                       x, Wq, Wk, Wv, gam, bet, mean, var, pa, Wout, bo, out);
}

// Round 5
// 87.853 us; speedup vs baseline: 1.0110x; 1.0052x over previous
//
#include <hip/hip_runtime.h>
#include <math.h>

// N=32768 tokens, B=32 batches, S=1024 keys/batch, H=512, OUT=32.
//
// Rank-2 collapse: score(i,j) = x_i^T (scale*Wq Wk^T) x_j  (2x2 M).
// w_i = softmax-weighted mean of x_j (2-vector). Softmax shift = 0: worst-case
// |score| <= |u||x| ~ 57 -> sum e^s <= ~8e26 < fp32 max; shift-invariant.
// BN folds into pair-SoA {A0,A1,C}; P = PReLU(w0*A0+w1*A1+C).
// y = P @ Wout + bout as bf16 MFMA 16x16x32 (R3-proven layouts).
//
// R12 = exact revert to R9 (best measured: 87.93 us). R10 (async-STAGE reg
// split, +0.9) and R11 (wave-local softmax, +0.4) both regressed/neutral:
// the prologue load latency is already TLP-hidden at 8 waves/CU, and the
// cross-wave LDS reduction + barrier cost ~= the broadcast-read advantage it
// buys. Kernel ~7us vs ~4.5us structural floor (1.7us trans-pipe exp floor,
// VALU-issue ~2.8us, launch/drain ~1us); window is 91.5% harness fills at
// 83-85% HBM peak. This is the keeper.
//  - packed f32 math (compiler-selected v_pk_fma_f32/v_pk_mul/v_pk_add)
//  - all bf16 packing via v_cvt_pk_bf16_f32 (RNE == manual bit trick)
//  - softmax on SoA keys (xsx/xsy), wave-uniform broadcast b128 reads
//  - epilogue BN+PReLU packed over pair-SoA LDS; PReLU = 0.5(1+a)z+0.5(1-a)|z|
// 512 blocks x 256 thr (2 blocks/CU, 8 waves/CU).

#define H_DIM   512
#define OUT_DIM 32
#define S_LEN   1024
#define THREADS 256
#define NW 4

#if __has_builtin(__builtin_amdgcn_exp2f)
#define EXP2(x) __builtin_amdgcn_exp2f(x)
#else
#define EXP2(x) exp2f(x)
#endif

typedef __attribute__((ext_vector_type(8))) short bf16x8;
typedef __attribute__((ext_vector_type(4))) float f32x4;
typedef __attribute__((ext_vector_type(2))) float f32x2;

__device__ __forceinline__ f32x2 pkfma(f32x2 a, f32x2 b, f32x2 c) {
    return __builtin_elementwise_fma(a, b, c);
}
// 2x f32 -> packed bf16 (lo from %1, hi from %2), RNE — matches old rne_bf16.
__device__ __forceinline__ unsigned int cvt_pk_bf16(float lo, float hi) {
    unsigned int r;
    asm("v_cvt_pk_bf16_f32 %0, %1, %2" : "=v"(r) : "v"(lo), "v"(hi));
    return r;
}

union frag_cast { unsigned int u[4]; int4 i4; bf16x8 v; };

__global__ __launch_bounds__(THREADS)
void fused_attn_kernel(const float* __restrict__ x,
                       const float* __restrict__ Wq,
                       const float* __restrict__ Wk,
                       const float* __restrict__ Wv,
                       const float* __restrict__ bn_gamma,
                       const float* __restrict__ bn_beta,
                       const float* __restrict__ bn_mean,
                       const float* __restrict__ bn_var,
                       const float* __restrict__ prelu_a,
                       const float* __restrict__ Wout,
                       const float* __restrict__ bout,
                       float* __restrict__ out)
{
    __shared__ __align__(16) float xsx[S_LEN]; // 4 KB, SoA key x-coords
    __shared__ __align__(16) float xsy[S_LEN]; // 4 KB, SoA key y-coords
    __shared__ float4 a01s[H_DIM / 2];        // 4 KB: {A0[2p],A0[2p+1],A1[2p],A1[2p+1]}
    __shared__ float2 cps[H_DIM / 2];         // 2 KB: {C[2p],C[2p+1]}
    __shared__ unsigned int bfr[32 * 64 * 4]; // 32 KB: bf16 B-frags, R3 ws layout
    __shared__ float redl[NW][64], redw0[NW][64], redw1[NW][64]; // 3 KB
    __shared__ float mred[NW][4];

    const int t    = threadIdx.x;
    const int lane = t & 63;
    const int q    = __builtin_amdgcn_readfirstlane(t >> 6);  // wave id 0..3
    const int b    = blockIdx.x >> 4;         // 16 blocks per batch
    const int tile = blockIdx.x & 15;
    const float scale = 0.044194173824159216f;  // 1/sqrt(512)
    const float L2E   = 1.4426950408889634f;

    // ---- stage batch x as SoA (tokens 2t,2t+1 per float4) ----
    const float4* xg = (const float4*)(x + (size_t)b * (S_LEN * 2));
    f32x2* xsx2 = (f32x2*)xsx;
    f32x2* xsy2 = (f32x2*)xsy;
    {
        float4 v0 = xg[t];
        float4 v1 = xg[t + 256];
        f32x2 a = {v0.x, v0.z}; xsx2[t] = a;
        f32x2 c = {v0.y, v0.w}; xsy2[t] = c;
        f32x2 d = {v1.x, v1.z}; xsx2[t + 256] = d;
        f32x2 e = {v1.y, v1.w}; xsy2[t + 256] = e;
    }

    // ---- fold BN into pair-SoA ABC (pair p = t, h = 2t, 2t+1) ----
    {
        const float2 gm = ((const float2*)bn_gamma)[t];
        const float2 vr = ((const float2*)bn_var)[t];
        const float2 bt = ((const float2*)bn_beta)[t];
        const float2 mn = ((const float2*)bn_mean)[t];
        const float2 wv0 = ((const float2*)Wv)[t];             // Wv[0][2t..]
        const float2 wv1 = ((const float2*)(Wv + H_DIM))[t];   // Wv[1][2t..]
        float g0 = gm.x * rsqrtf(vr.x + 1e-5f);
        float g1 = gm.y * rsqrtf(vr.y + 1e-5f);
        a01s[t] = make_float4(wv0.x * g0, wv0.y * g1, wv1.x * g0, wv1.y * g1);
        cps[t]  = make_float2(bt.x - mn.x * g0, bt.y - mn.y * g1);
    }

    // ---- M = Wq Wk^T partials ----
    {
        float m00 = 0.f, m01 = 0.f, m10 = 0.f, m11 = 0.f;
        #pragma unroll
        for (int k = 0; k < 2; ++k) {
            int h = t + k * 256;
            float a0 = Wq[h], a1 = Wq[H_DIM + h];
            float b0 = Wk[h], b1 = Wk[H_DIM + h];
            m00 = fmaf(a0, b0, m00); m01 = fmaf(a0, b1, m01);
            m10 = fmaf(a1, b0, m10); m11 = fmaf(a1, b1, m11);
        }
        #pragma unroll
        for (int off = 32; off >= 1; off >>= 1) {
            m00 += __shfl_xor(m00, off); m01 += __shfl_xor(m01, off);
            m10 += __shfl_xor(m10, off); m11 += __shfl_xor(m11, off);
        }
        if (lane == 0) {
            mred[q][0] = m00; mred[q][1] = m01;
            mred[q][2] = m10; mred[q][3] = m11;
        }
    }

    // ---- pack Wout -> bf16 B-frags in LDS (R3 setup's exact flat layout) ----
    // flat u32 index F = f*256 + l*4 + jj, f = nt*16+s, l = quad*16+c:
    //   bfr[F] = pack(Wout[s*32+quad*8+2jj][nt*16+c], Wout[s*32+quad*8+2jj+1][nt*16+c])
    // thread mapping i = k*256+t decodes c fastest for coalesced Wout reads.
    #pragma unroll
    for (int k = 0; k < 32; ++k) {
        int i    = k * 256 + t;
        int c    = i & 15;
        int jj   = (i >> 4) & 3;
        int quad = (i >> 6) & 3;
        int s    = (i >> 8) & 15;
        int nt   = (i >> 12) & 1;
        int h    = s * 32 + quad * 8 + 2 * jj;
        int o    = nt * 16 + c;
        float f0 = Wout[h * 32 + o];
        float f1 = Wout[(h + 1) * 32 + o];
        int F = (nt * 16 + s) * 256 + (quad * 16 + c) * 4 + jj;
        bfr[F] = cvt_pk_bf16(f0, f1);
    }
    __syncthreads();   // xs*, a01s/cps, mred, bfr all visible

    float m00 = (mred[0][0] + mred[1][0] + mred[2][0] + mred[3][0]) * scale;
    float m01 = (mred[0][1] + mred[1][1] + mred[2][1] + mred[3][1]) * scale;
    float m10 = (mred[0][2] + mred[1][2] + mred[2][2] + mred[3][2]) * scale;
    float m11 = (mred[0][3] + mred[1][3] + mred[2][3] + mred[3][3]) * scale;

    // ---- per-token u (lane = token), no shift (log2e folded) ----
    const float xtx = xsx[tile * 64 + lane];
    const float xty = xsy[tile * 64 + lane];
    const float u0L = fmaf(xtx, m00, xty * m10) * L2E;
    const float u1L = fmaf(xtx, m01, xty * m11) * L2E;
    const f32x2 u0L2 = {u0L, u0L};
    const f32x2 u1L2 = {u1L, u1L};

    // ---- fused softmax pass: wave q covers keys [q*256, q*256+256) ----
    // 4 keys/iter; packed f32 pairs (even/odd accumulation chains).
    f32x2 l2  = {0.f, 0.f};
    f32x2 w02 = {0.f, 0.f};
    f32x2 w12 = {0.f, 0.f};
    const float4* kx4 = (const float4*)(xsx + q * 256);
    const float4* ky4 = (const float4*)(xsy + q * 256);
    #pragma unroll 4
    for (int i = 0; i < 64; ++i) {
        float4 kx = kx4[i];                 // wave-uniform addr -> broadcast
        float4 ky = ky4[i];
        f32x2 kxa = {kx.x, kx.y};
        f32x2 kxb = {kx.z, kx.w};
        f32x2 kya = {ky.x, ky.y};
        f32x2 kyb = {ky.z, ky.w};
        f32x2 arga = pkfma(u0L2, kxa, u1L2 * kya);
        f32x2 argb = pkfma(u0L2, kxb, u1L2 * kyb);
        f32x2 ea = {EXP2(arga.x), EXP2(arga.y)};
        f32x2 eb = {EXP2(argb.x), EXP2(argb.y)};
        l2  = l2 + ea + eb;
        w02 = pkfma(ea, kxa, w02);
        w02 = pkfma(eb, kxb, w02);
        w12 = pkfma(ea, kya, w12);
        w12 = pkfma(eb, kyb, w12);
    }
    float l  = l2.x + l2.y;
    float w0 = w02.x + w02.y;
    float w1 = w12.x + w12.y;
    redl[q][lane] = l; redw0[q][lane] = w0; redw1[q][lane] = w1;
    __syncthreads();
    l  = redl[0][lane]  + redl[1][lane]  + redl[2][lane]  + redl[3][lane];
    w0 = redw0[0][lane] + redw0[1][lane] + redw0[2][lane] + redw0[3][lane];
    w1 = redw1[0][lane] + redw1[1][lane] + redw1[2][lane] + redw1[3][lane];
    const float inv = 1.0f / l;
    w0 *= inv; w1 *= inv;

    // redistribute: wave q's MFMA tile = tokens q*16..q*16+15; m = lane&15
    const int src = q * 16 + (lane & 15);
    const float w0t = __shfl(w0, src);
    const float w1t = __shfl(w1, src);
    const f32x2 w0t2 = {w0t, w0t};
    const f32x2 w1t2 = {w1t, w1t};

    // ---- MFMA epilogue: y[16 tok x 32 out] = P[16 x 512] @ Wout[512 x 32] ----
    // PReLU(z) = 0.5(1+a)z + 0.5(1-a)|z|  (exact for both signs)
    const float ap = prelu_a[0];
    const f32x2 ca2 = {0.5f * (1.f + ap), 0.5f * (1.f + ap)};
    const f32x2 cb2 = {0.5f * (1.f - ap), 0.5f * (1.f - ap)};
    const int quad = lane >> 4;
    f32x4 acc0 = {0.f, 0.f, 0.f, 0.f};
    f32x4 acc1 = {0.f, 0.f, 0.f, 0.f};
    const int4* bsrc = (const int4*)bfr;

    for (int s = 0; s < 16; ++s) {
        frag_cast bf0, bf1;                 // ds_read_b128, 2-way alias = free
        bf0.i4 = bsrc[s * 64 + lane];
        bf1.i4 = bsrc[(16 + s) * 64 + lane];
        const int hb2 = s * 16 + quad * 4;  // h-pair index base
        frag_cast af;
        #pragma unroll
        for (int jj = 0; jj < 4; ++jj) {
            float4 a = a01s[hb2 + jj];      // broadcast ds_read_b128
            float2 cc2 = cps[hb2 + jj];     // broadcast ds_read_b64
            f32x2 a0 = {a.x, a.y};
            f32x2 a1 = {a.z, a.w};
            f32x2 cc = {cc2.x, cc2.y};
            f32x2 z  = pkfma(w0t2, a0, pkfma(w1t2, a1, cc));
            f32x2 az = __builtin_elementwise_abs(z);
            f32x2 p  = pkfma(ca2, z, cb2 * az);
            af.u[jj] = cvt_pk_bf16(p.x, p.y);
        }
        acc0 = __builtin_amdgcn_mfma_f32_16x16x32_bf16(af.v, bf0.v, acc0, 0, 0, 0);
        acc1 = __builtin_amdgcn_mfma_f32_16x16x32_bf16(af.v, bf1.v, acc1, 0, 0, 0);
    }

    // ---- store: D col=lane&15 (out), row=quad*4+r (token) ----
    const size_t base = (size_t)(b * S_LEN + tile * 64) * OUT_DIM;
    const int o0 = lane & 15;
    const float bo0 = bout[o0], bo1 = bout[16 + o0];
    #pragma unroll
    for (int r = 0; r < 4; ++r) {
        const int tt = q * 16 + quad * 4 + r;
        out[base + tt * 32 + o0]      = acc0[r] + bo0;
        out[base + tt * 32 + 16 + o0] = acc1[r] + bo1;
    }
}

extern "C" void kernel_launch(void* const* d_in, const int* in_sizes, int n_in,
                              void* d_out, int out_size, void* d_ws, size_t ws_size,
                              hipStream_t stream) {
    const float* x    = (const float*)d_in[0];
    const float* Wq   = (const float*)d_in[2];
    const float* Wk   = (const float*)d_in[3];
    const float* Wv   = (const float*)d_in[4];
    const float* gam  = (const float*)d_in[5];
    const float* bet  = (const float*)d_in[6];
    const float* mean = (const float*)d_in[7];
    const float* var  = (const float*)d_in[8];
    const float* pa   = (const float*)d_in[9];
    const float* Wout = (const float*)d_in[10];
    const float* bo   = (const float*)d_in[11];
    float* out = (float*)d_out;

    const int N = in_sizes[0] / 2;          // 32768 tokens
    const int blocks = N / 64;              // 512
    hipLaunchKernelGGL(fused_attn_kernel, dim3(blocks), dim3(THREADS), 0, stream,
                       x, Wq, Wk, Wv, gam, bet, mean, var, pa, Wout, bo, out);
}